// Round 12
// baseline (548.968 us; speedup 1.0000x reference)
//
#include <hip/hip_runtime.h>
#include <hip/hip_bf16.h>

using bf16 = __hip_bfloat16;
typedef __attribute__((ext_vector_type(8))) short bf16x8;
typedef __attribute__((ext_vector_type(4))) float f32x4;

#define DEV __device__ __forceinline__

#define AS1 __attribute__((address_space(1)))
#define AS3 __attribute__((address_space(3)))
#define SB  __builtin_amdgcn_sched_barrier(0)
#define BARR __builtin_amdgcn_s_barrier()
#define LG0 asm volatile("s_waitcnt lgkmcnt(0)" ::: "memory")
#define VM2 asm volatile("s_waitcnt vmcnt(2)" ::: "memory")
#define VM0 asm volatile("s_waitcnt vmcnt(0)" ::: "memory")

// ---------------------------------------------------------------------------
// constants
static constexpr int Bsz = 8, Nseq = 512, Dm = 768, Vv = 30000, Yv = 30000;
static constexpr int Ypad = 30208;               // 118 tiles of 256
static constexpr int Tok = Bsz * Nseq;           // 4096
static constexpr int NT = Dm / 32;               // 24 K-tiles of 32

// ---------------------------------------------------------------------------
// Big GEMM: C[4096][Yv] f32 = A[4096][768]*B[Ypad][768]^T
// 128M x 256N tile, BK=32, 8 waves, 2 blocks/CU. A-fragments loaded DIRECTLY
// global->VGPR (L1-resident 8KB k-slice; LDS traffic -45%). B double-streamed
// through 6 LDS chunks (48 KiB, 3 groups of {B0,B1}), 3 phases per 3 K-tiles,
// vmcnt(2) cadence, XOR-swizzled B reads, XCD swizzle, nt stores.
__global__ __launch_bounds__(512, 4)
void gemm_big(const bf16* __restrict__ Ag, const bf16* __restrict__ Bg,
              float* __restrict__ Cg)
{
    __shared__ bf16 sm[6][4096];                 // 6 x 8 KiB = 48 KiB

    int bid = blockIdx.x;
    { int cpx = gridDim.x >> 3; bid = (bid & 7) * cpx + (bid >> 3); }
    const int mT = bid & 31;
    const int nT = bid >> 5;

    const int tid  = threadIdx.x;
    const int lane = tid & 63;
    const int wid  = tid >> 6;
    const int wm   = wid >> 2;
    const int wn   = wid & 3;

    // B staging (global_load_lds): thread covers 16B chunk; XOR-swizzle
    const int lr = tid >> 2;
    const int sc = ((tid & 3) ^ (lr & 3)) << 3;
    const bf16* bS0 = Bg + (long)(nT * 256 + lr) * Dm + sc;
    const bf16* bS1 = bS0 + (long)128 * Dm;
    const int ldsW = wid << 9;

    // fragment geometry
    const int fl = lane & 15;
    const int fh = lane >> 4;
    const int e0 = (fh ^ (fl & 3)) << 3;
    const int bro = (wn * 32 + fl) * 32;

    // A direct-load base: lane reads A[(mT*128 + wm*64 + mm*16 + fl)*Dm + t*32 + fh*8]
    const bf16* aF = Ag + (long)(mT * 128 + wm * 64 + fl) * Dm + fh * 8;

    bf16x8 afr[4], b0r[2], b1r[2];
    f32x4 acc[4][2][2] = {};

#define STG(CI, PTR, T)                                                        \
    __builtin_amdgcn_global_load_lds((const AS1 void*)((PTR) + (T) * 32),      \
        (AS3 void*)&sm[CI][ldsW], 16, 0, 0);
#define STGG(G, T)  STG(2*(G), bS0, T) STG(2*(G) + 1, bS1, T)
#define AF(T)                                                                  \
    _Pragma("unroll") for (int mm = 0; mm < 4; ++mm)                           \
        afr[mm] = *(const bf16x8*)(aF + (long)(mm * 16) * Dm + (T) * 32);
#define RB(BR, CI)                                                             \
    _Pragma("unroll") for (int nn = 0; nn < 2; ++nn)                           \
        BR[nn] = *(const bf16x8*)&sm[CI][bro + nn * 512 + e0];
#define RGB(G)  RB(b0r, 2*(G)) RB(b1r, 2*(G)+1)
#define MF16                                                                   \
    __builtin_amdgcn_s_setprio(1);                                             \
    _Pragma("unroll") for (int mm = 0; mm < 4; ++mm)                           \
    _Pragma("unroll") for (int nn = 0; nn < 2; ++nn)                           \
        acc[mm][0][nn] = __builtin_amdgcn_mfma_f32_16x16x32_bf16(              \
            afr[mm], b0r[nn], acc[mm][0][nn], 0, 0, 0);                        \
    _Pragma("unroll") for (int mm = 0; mm < 4; ++mm)                           \
    _Pragma("unroll") for (int nn = 0; nn < 2; ++nn)                           \
        acc[mm][1][nn] = __builtin_amdgcn_mfma_f32_16x16x32_bf16(              \
            afr[mm], b1r[nn], acc[mm][1][nn], 0, 0, 0);                        \
    __builtin_amdgcn_s_setprio(0);

    // prologue: B g0 <- tile 0, g1 <- tile 1; confirm g0 (g1 stays in flight)
    STGG(0, 0) STGG(1, 1)
    VM2; SB; BARR; SB;

    // main loop: 7 iters; phase (tile t, group g): af(t) | readB(g) |
    // stageB(g+2 <- t+2) | VM2 (retires af + stage of t+1) | barrier | MFMA
#pragma unroll 1
    for (int t = 0; t < NT - 3; t += 3) {
        // phase A: tile t (g0), stage g2 <- t+2
        AF(t)
        RGB(0)
        STGG(2, t + 2)
        VM2; SB; BARR; LG0; SB;
        MF16
        SB; BARR; SB;
        // phase B: tile t+1 (g1), stage g0 <- t+3
        AF(t + 1)
        RGB(1)
        STGG(0, t + 3)
        VM2; SB; BARR; LG0; SB;
        MF16
        SB; BARR; SB;
        // phase C: tile t+2 (g2), stage g1 <- t+4
        AF(t + 2)
        RGB(2)
        STGG(1, t + 4)
        VM2; SB; BARR; LG0; SB;
        MF16
        SB; BARR; SB;
    }

    // tail: tiles 21,22,23
    {
        // tile 21 (g0), stage g2 <- 23
        AF(NT - 3)
        RGB(0)
        STGG(2, NT - 1)
        VM2; SB; BARR; LG0; SB;
        MF16
        SB; BARR; SB;
        // tile 22 (g1); drain
        AF(NT - 2)
        RGB(1)
        VM0; SB; BARR; LG0; SB;
        MF16
        SB; BARR; SB;
        // tile 23 (g2)
        AF(NT - 1)
        RGB(2)
        VM0; SB; LG0; SB;
        MF16
    }

    // epilogue: nt dword stores; drain overlaps the co-resident block
    const int rB = mT * 128 + wm * 64 + fh * 4;
    const int cB = nT * 256 + wn * 32 + fl;
#pragma unroll
    for (int mm = 0; mm < 4; ++mm)
#pragma unroll
    for (int nq = 0; nq < 2; ++nq)
#pragma unroll
    for (int nn = 0; nn < 2; ++nn) {
        const int c = cB + nq * 128 + nn * 16;
        if (c >= Yv) continue;
        const int r = rB + mm * 16;
#pragma unroll
        for (int j = 0; j < 4; ++j)
            __builtin_nontemporal_store(acc[mm][nq][nn][j],
                                        Cg + (long)(r + j) * Yv + c);
    }
#undef STG
#undef STGG
#undef AF
#undef RB
#undef RGB
#undef MF16
}

// ---------------------------------------------------------------------------
// Shared GEMM body: C[M][*] = A[M][K](lda) * B[*][K](ldb)^T, 128x128 tile.
// smem must be 128*32*2 bf16 (16 KiB). Verified m97 structure.
template<bool STORE_BF16>
DEV void gemm_core(bf16* __restrict__ smem,
                   const bf16* __restrict__ A, const bf16* __restrict__ Bm,
                   void* __restrict__ Cg, int bid, int M, int K,
                   int lda, int ldb, int ldc)
{
    bf16* As = smem;
    bf16* Bs = smem + 128 * 32;

    const int nTilesM = M >> 7;
    const int mTile = bid % nTilesM;
    const int nTile = bid / nTilesM;

    const int tid  = threadIdx.x;
    const int wave = tid >> 6;
    const int lane = tid & 63;

    const int sRow = (wave << 4) + (lane >> 2);
    const int sCol = (lane & 3) << 3;

    const long aBase = (long)(mTile * 128) * lda;
    const long bBase = (long)(nTile * 128) * ldb;

    const int fl = lane & 15;
    const int fh = lane >> 4;
    const int wRow = (wave >> 1) << 6;
    const int wCol = (wave & 1) << 6;

    f32x4 acc[4][4] = {};

    for (int k0 = 0; k0 < K; k0 += 32) {
#pragma unroll
        for (int t = 0; t < 2; ++t) {
            const bf16* gA = A  + aBase + (long)(t * 64 + sRow) * lda + (k0 + sCol);
            const bf16* gB = Bm + bBase + (long)(t * 64 + sRow) * ldb + (k0 + sCol);
            bf16* lA = &As[(t * 64 + (wave << 4)) * 32];
            bf16* lB = &Bs[(t * 64 + (wave << 4)) * 32];
            __builtin_amdgcn_global_load_lds(
                (const AS1 void*)gA, (AS3 void*)lA, 16, 0, 0);
            __builtin_amdgcn_global_load_lds(
                (const AS1 void*)gB, (AS3 void*)lB, 16, 0, 0);
        }
        __syncthreads();

        bf16x8 af[4], bfg[4];
#pragma unroll
        for (int m = 0; m < 4; ++m)
            af[m] = *(const bf16x8*)&As[(wRow + m * 16 + fl) * 32 + fh * 8];
#pragma unroll
        for (int n = 0; n < 4; ++n)
            bfg[n] = *(const bf16x8*)&Bs[(wCol + n * 16 + fl) * 32 + fh * 8];
#pragma unroll
        for (int m = 0; m < 4; ++m)
#pragma unroll
            for (int n = 0; n < 4; ++n)
                acc[m][n] = __builtin_amdgcn_mfma_f32_16x16x32_bf16(
                    af[m], bfg[n], acc[m][n], 0, 0, 0);
        __syncthreads();
    }

    const int rBase = mTile * 128 + wRow + fh * 4;
    const int cBase = nTile * 128 + wCol + fl;
#pragma unroll
    for (int m = 0; m < 4; ++m) {
#pragma unroll
        for (int n = 0; n < 4; ++n) {
            int gc = cBase + n * 16;
            int gr = rBase + m * 16;
            if (STORE_BF16) {
                bf16* C = (bf16*)Cg;
#pragma unroll
                for (int j = 0; j < 4; ++j)
                    C[(long)(gr + j) * ldc + gc] = __float2bfloat16(acc[m][n][j]);
            } else {
                float* C = (float*)Cg;
#pragma unroll
                for (int j = 0; j < 4; ++j)
                    C[(long)(gr + j) * ldc + gc] = acc[m][n][j];
            }
        }
    }
}

// batched wrapper (step 5)
template<bool STORE_BF16>
__global__ __launch_bounds__(256)
void gemm_bt(const bf16* __restrict__ Ag, const bf16* __restrict__ Bg,
             void* __restrict__ Cg, int M, int K,
             int lda, int ldb, int ldc, long sA, long sB, long sC)
{
    __shared__ bf16 smem[128 * 32 * 2];
    const int bz = blockIdx.z;
    char* C = (char*)Cg + (long)bz * sC * (STORE_BF16 ? 2 : 4);
    gemm_core<STORE_BF16>(smem, Ag + (long)bz * sA, Bg + (long)bz * sB,
                          (void*)C, blockIdx.x, M, K, lda, ldb, ldc);
}

// fused dual GEMM (step 2): blocks [0,192) QW = X@W_A^T ; [192,384) XWo^T = W_O^T@X^T
__global__ __launch_bounds__(256)
void gemm_dual(const bf16* __restrict__ Xb, const bf16* __restrict__ Wcat,
               bf16* __restrict__ QWb, bf16* __restrict__ XWoT)
{
    __shared__ bf16 smem[128 * 32 * 2];
    const int bid = blockIdx.x;
    if (bid < 192)
        gemm_core<true>(smem, Xb, Wcat, (void*)QWb, bid, Tok, Dm, Dm, Dm, Dm);
    else
        gemm_core<true>(smem, Wcat + (size_t)Dm * Dm, Xb, (void*)XWoT,
                        bid - 192, Dm, Dm, Dm, Dm, Tok);
}

// ---------------------------------------------------------------------------
// 64x128-tile GEMM (bf16 out): C[M][Nc] = A[M][K](lda) * B[Nc][K]^T
// 4 waves, each computes 64x32. For the logits GEMM (fills 256 blocks).
__global__ __launch_bounds__(256)
void gemm_bt64(const bf16* __restrict__ Ag, const bf16* __restrict__ Bg,
               bf16* __restrict__ Cg, int M, int K, int lda, int ldc,
               long sA, long sB, long sC)
{
    __shared__ bf16 As[64 * 32];
    __shared__ bf16 Bs[128 * 32];

    const int bz = blockIdx.z;
    const bf16* A  = Ag + (long)bz * sA;
    const bf16* Bm = Bg + (long)bz * sB;
    bf16* C = Cg + (long)bz * sC;

    const int bid = blockIdx.x;
    const int nTilesM = M >> 6;
    const int mTile = bid % nTilesM;
    const int nTile = bid / nTilesM;

    const int tid  = threadIdx.x;
    const int wave = tid >> 6;
    const int lane = tid & 63;

    const int sRow = tid >> 2;
    const int sCol = (tid & 3) << 3;

    const long aBase = (long)(mTile * 64) * lda;
    const long bBase = (long)(nTile * 128) * K;

    const int fl = lane & 15;
    const int fh = lane >> 4;

    f32x4 acc[4][2] = {};

    for (int k0 = 0; k0 < K; k0 += 32) {
        __builtin_amdgcn_global_load_lds(
            (const AS1 void*)(A + aBase + (long)sRow * lda + (k0 + sCol)),
            (AS3 void*)&As[wave * 512], 16, 0, 0);
#pragma unroll
        for (int t = 0; t < 2; ++t)
            __builtin_amdgcn_global_load_lds(
                (const AS1 void*)(Bm + bBase + (long)(t * 64 + sRow) * K + (k0 + sCol)),
                (AS3 void*)&Bs[t * 2048 + wave * 512], 16, 0, 0);
        __syncthreads();

        bf16x8 af[4], bfg[2];
#pragma unroll
        for (int m = 0; m < 4; ++m)
            af[m] = *(const bf16x8*)&As[(m * 16 + fl) * 32 + fh * 8];
#pragma unroll
        for (int n = 0; n < 2; ++n)
            bfg[n] = *(const bf16x8*)&Bs[(wave * 32 + n * 16 + fl) * 32 + fh * 8];
#pragma unroll
        for (int m = 0; m < 4; ++m)
#pragma unroll
            for (int n = 0; n < 2; ++n)
                acc[m][n] = __builtin_amdgcn_mfma_f32_16x16x32_bf16(
                    af[m], bfg[n], acc[m][n], 0, 0, 0);
        __syncthreads();
    }

    const int rBase = mTile * 64 + fh * 4;
    const int cBase = nTile * 128 + wave * 32 + fl;
#pragma unroll
    for (int m = 0; m < 4; ++m)
#pragma unroll
    for (int n = 0; n < 2; ++n) {
        const int gc = cBase + n * 16;
        const int gr = rBase + m * 16;
#pragma unroll
        for (int j = 0; j < 4; ++j)
            C[(long)(gr + j) * ldc + gc] = __float2bfloat16(acc[m][n][j]);
    }
}

// ---------------------------------------------------------------------------
// Fused prep: [0,11328) cvt_ey | [11328,12480) wT | [12480,16576) gather
static constexpr int PREP_CVT = 11328, PREP_WT = 1152, PREP_GATHER = 4096;

__global__ __launch_bounds__(256)
void k_prep(const float* __restrict__ Ey, bf16* __restrict__ Eyb,
            const float* __restrict__ WA, const float* __restrict__ WO,
            bf16* __restrict__ Wcat,
            const int* __restrict__ Ms, const float* __restrict__ Ev,
            bf16* __restrict__ Xb)
{
    __shared__ float t[32][33];
    const int b = blockIdx.x;
    const int tid = threadIdx.x;

    if (b < PREP_CVT) {
        const long idx = ((long)b * 256 + tid) * 8;
        const int row = (int)(idx / Dm);
        union { bf16 h[8]; uint4 u; } pk;
        if (row < Yv) {
            const f32x4* s = (const f32x4*)(Ey + idx);
            f32x4 a = __builtin_nontemporal_load(s);
            f32x4 c = __builtin_nontemporal_load(s + 1);
#pragma unroll
            for (int i = 0; i < 4; ++i) {
                pk.h[i]     = __float2bfloat16(a[i]);
                pk.h[4 + i] = __float2bfloat16(c[i]);
            }
        } else {
#pragma unroll
            for (int i = 0; i < 8; ++i) pk.h[i] = __float2bfloat16(0.f);
        }
        *(uint4*)(Eyb + idx) = pk.u;
    } else if (b < PREP_CVT + PREP_WT) {
        const int rem = b - PREP_CVT;
        const int z = rem / 576, r2 = rem % 576;
        const int bx = (r2 % 24) * 32, by = (r2 / 24) * 32;
        const float* W = z ? WO : WA;
        bf16* WT = Wcat + (size_t)z * Dm * Dm;
        const int tx = tid & 31, ty = tid >> 5;
#pragma unroll
        for (int i = 0; i < 32; i += 8)
            t[ty + i][tx] = W[(long)(bx + ty + i) * Dm + (by + tx)];
        __syncthreads();
#pragma unroll
        for (int i = 0; i < 32; i += 8)
            WT[(long)(by + ty + i) * Dm + (bx + tx)] = __float2bfloat16(t[tx][ty + i]);
    } else {
        const int token = b - (PREP_CVT + PREP_WT);
        if (tid < 192) {
            const int id = Ms[token];
            const int d = tid * 4;
            float4 v = *(const float4*)(Ev + (long)id * Dm + d);
            union { bf16 h[4]; uint2 u; } pk;
            pk.h[0] = __float2bfloat16(v.x); pk.h[1] = __float2bfloat16(v.y);
            pk.h[2] = __float2bfloat16(v.z); pk.h[3] = __float2bfloat16(v.w);
            *(uint2*)(Xb + (long)token * Dm + d) = pk.u;
        }
    }
}

// ---------------------------------------------------------------------------
DEV float waveMax(float v) {
#pragma unroll
    for (int o = 32; o > 0; o >>= 1) v = fmaxf(v, __shfl_xor(v, o, 64));
    return v;
}
DEV float waveSum(float v) {
#pragma unroll
    for (int o = 32; o > 0; o >>= 1) v += __shfl_xor(v, o, 64);
    return v;
}

// softmax over j of (L[b,i,j] + (j-i)) with mask; L is bf16, bias in f32
__global__ __launch_bounds__(256) void k_softmax(const bf16* __restrict__ L,
                                                 const int* __restrict__ Ms,
                                                 float* __restrict__ Aout,
                                                 bf16* __restrict__ Ab)
{
    __shared__ float red[8];
    int row = blockIdx.x;
    int b = row >> 9, i = row & 511;
    const bf16* l = L + (long)row * Nseq;
    const int* ms = Ms + (b << 9);
    int t = threadIdx.x;
    int wid = t >> 6, lane = t & 63;
    int j0 = t, j1 = t + 256;

    float a0 = __bfloat162float(l[j0]) + (float)(j0 - i);
    float a1 = __bfloat162float(l[j1]) + (float)(j1 - i);
    if (ms[j0] == 0) a0 = -1e12f;
    if (ms[j1] == 0) a1 = -1e12f;

    float m = waveMax(fmaxf(a0, a1));
    if (lane == 0) red[wid] = m;
    __syncthreads();
    m = fmaxf(fmaxf(red[0], red[1]), fmaxf(red[2], red[3]));

    float e0 = expf(a0 - m), e1 = expf(a1 - m);
    float s = waveSum(e0 + e1);
    if (lane == 0) red[4 + wid] = s;
    __syncthreads();
    s = red[4] + red[5] + red[6] + red[7];
    float inv = 1.0f / s;

    float r0 = e0 * inv, r1 = e1 * inv;
    __builtin_nontemporal_store(r0, &Aout[(long)row * Nseq + j0]);
    __builtin_nontemporal_store(r1, &Aout[(long)row * Nseq + j1]);
    Ab[(long)row * Nseq + j0] = __float2bfloat16(r0);
    Ab[(long)row * Nseq + j1] = __float2bfloat16(r1);
}

// H = LN(Qc + X) * gamma + beta  -> bf16  (Qc and X read as bf16)
__global__ __launch_bounds__(256) void k_ln(const bf16* __restrict__ Qc,
                                            const bf16* __restrict__ Xb,
                                            const float* __restrict__ gamma,
                                            const float* __restrict__ beta,
                                            bf16* __restrict__ Hb)
{
    __shared__ float red[8];
    int row = blockIdx.x;
    const bf16* q = Qc + (long)row * Dm;
    const bf16* e = Xb + (long)row * Dm;
    int t = threadIdx.x;
    int wid = t >> 6, lane = t & 63;

    float x[3];
#pragma unroll
    for (int c = 0; c < 3; ++c)
        x[c] = __bfloat162float(q[t + c * 256]) + __bfloat162float(e[t + c * 256]);

    float s = waveSum(x[0] + x[1] + x[2]);
    if (lane == 0) red[wid] = s;
    __syncthreads();
    float mu = (red[0] + red[1] + red[2] + red[3]) * (1.0f / 768.0f);

    float vs = 0.f;
#pragma unroll
    for (int c = 0; c < 3; ++c) { float d = x[c] - mu; vs += d * d; }
    vs = waveSum(vs);
    if (lane == 0) red[4 + wid] = vs;
    __syncthreads();
    float var = (red[4] + red[5] + red[6] + red[7]) * (1.0f / 768.0f);
    float rstd = rsqrtf(var + 1e-5f);

#pragma unroll
    for (int c = 0; c < 3; ++c) {
        int d = t + c * 256;
        Hb[(long)row * Dm + d] =
            __float2bfloat16((x[c] - mu) * rstd * gamma[d] + beta[d]);
    }
}

// ---------------------------------------------------------------------------
extern "C" void kernel_launch(void* const* d_in, const int* in_sizes, int n_in,
                              void* d_out, int out_size, void* d_ws, size_t ws_size,
                              hipStream_t stream)
{
    const int*   Ms    = (const int*)d_in[0];
    const float* Ev    = (const float*)d_in[1];
    const float* Ey    = (const float*)d_in[2];
    const float* WA    = (const float*)d_in[3];
    const float* WO    = (const float*)d_in[4];
    const float* gamma = (const float*)d_in[5];
    const float* beta  = (const float*)d_in[6];

    float* y_out = (float*)d_out;                       // [4096][30000]
    float* A_out = y_out + (size_t)Tok * Yv;            // [8][512][512]

    char* ws = (char*)d_ws;
    size_t off = 0;
    auto alloc = [&](size_t n) { char* p = ws + off; off += (n + 255) & ~(size_t)255; return p; };
    bf16*  Xb    = (bf16*) alloc((size_t)Tok * Dm * 2);
    bf16*  WcatT = (bf16*) alloc((size_t)2 * Dm * Dm * 2);
    bf16*  QWb   = (bf16*) alloc((size_t)Tok * Dm * 2);
    bf16*  XWoT  = (bf16*) alloc((size_t)Dm * Tok * 2);  // [768][4096]
    bf16*  Lb    = (bf16*) alloc((size_t)Tok * Nseq * 2);
    bf16*  Ab    = (bf16*) alloc((size_t)Tok * Nseq * 2);
    bf16*  Qcb   = (bf16*) alloc((size_t)Tok * Dm * 2);
    bf16*  Hb    = (bf16*) alloc((size_t)Tok * Dm * 2);
    bf16*  Eyb   = (bf16*) alloc((size_t)Ypad * Dm * 2);

    // 1. fused prep: E_y convert+pad | W transpose | embedding gather
    k_prep<<<dim3(PREP_CVT + PREP_WT + PREP_GATHER), dim3(256), 0, stream>>>(
        Ey, Eyb, WA, WO, WcatT, Ms, Ev, Xb);
    // 2. fused dual GEMM: QW = X@W_A^T  |  XWo^T = W_O^T@X^T  (384 blocks)
    gemm_dual<<<dim3(384), dim3(256), 0, stream>>>(Xb, WcatT, QWb, XWoT);
    // 3. logits = QW @ X^T per batch (bf16 out, 64x128 tiles, 256 blocks)
    gemm_bt64<<<dim3(32, 1, 8), dim3(256), 0, stream>>>(
        QWb, Xb, Lb, Nseq, Dm, Dm, Nseq,
        (long)Nseq * Dm, (long)Nseq * Dm, (long)Nseq * Nseq);
    // 4. bias + mask + softmax -> A (f32 in d_out, nt) and Ab (bf16)
    k_softmax<<<dim3(Tok), dim3(256), 0, stream>>>(Lb, Ms, A_out, Ab);
    // 5. Qc = A @ XWo per batch (bf16 out; B = XWo^T column-slice, ldb=4096)
    gemm_bt<true><<<dim3(24, 1, 8), dim3(256), 0, stream>>>(
        Ab, XWoT, (void*)Qcb, Nseq, Nseq, Nseq, Tok, Dm,
        (long)Nseq * Nseq, (long)Nseq, (long)Nseq * Dm);
    // 6. H = LN(Qc + X)
    k_ln<<<dim3(Tok), dim3(256), 0, stream>>>(Qcb, Xb, gamma, beta, Hb);
    // 7. y_logits = H @ E_y^T  (A-direct 128x256 BK=32, 3-phase, 2 blocks/CU)
    gemm_big<<<dim3(32 * (Ypad / 256)), dim3(512), 0, stream>>>(Hb, Eyb, y_out);
}

// Round 13
// 340.188 us; speedup vs baseline: 1.6137x; 1.6137x over previous
//
#include <hip/hip_runtime.h>
#include <hip/hip_bf16.h>

using bf16 = __hip_bfloat16;
typedef __attribute__((ext_vector_type(8))) short bf16x8;
typedef __attribute__((ext_vector_type(4))) float f32x4;

#define DEV __device__ __forceinline__

#define AS1 __attribute__((address_space(1)))
#define AS3 __attribute__((address_space(3)))
#define SB  __builtin_amdgcn_sched_barrier(0)
#define BARR __builtin_amdgcn_s_barrier()
#define LG0 asm volatile("s_waitcnt lgkmcnt(0)" ::: "memory")
#define VM3 asm volatile("s_waitcnt vmcnt(3)" ::: "memory")
#define VM0 asm volatile("s_waitcnt vmcnt(0)" ::: "memory")

// ---------------------------------------------------------------------------
// constants
static constexpr int Bsz = 8, Nseq = 512, Dm = 768, Vv = 30000, Yv = 30000;
static constexpr int Ypad = 30208;               // 118 tiles of 256
static constexpr int Tok = Bsz * Nseq;           // 4096
static constexpr int NT = Dm / 32;               // 24 K-tiles of 32

// ---------------------------------------------------------------------------
// Big GEMM (round-11 verified best): C[4096][Yv] f32 = A[4096][768]*B^T
// 128M x 256N tile, BK=32, 8 waves, 9 chunks (3 K-tile groups) = 72 KiB LDS
// -> 2 blocks/CU. 3 phases per 3 K-tiles (2 barriers/K-tile, 16 MFMA/phase),
// vmcnt(3) cadence (stage tile p+2 at phase p; confirm tile p+1), XOR-swizzle,
// XCD swizzle, nt stores. Groups: g0={0,1,2} g1={3,4,5} g2={6,7,8} (A,B0,B1).
// NOTE (r12 lesson): A-direct-to-VGPR variant spills (>128 VGPR at 2 blk/CU;
// WRITE_SIZE +176MB scratch) -- keep A staged through LDS.
__global__ __launch_bounds__(512, 4)
void gemm_big(const bf16* __restrict__ Ag, const bf16* __restrict__ Bg,
              float* __restrict__ Cg)
{
    __shared__ bf16 sm[9][4096];                 // 9 x 8 KiB = 72 KiB

    int bid = blockIdx.x;
    { int cpx = gridDim.x >> 3; bid = (bid & 7) * cpx + (bid >> 3); }
    const int mT = bid & 31;
    const int nT = bid >> 5;

    const int tid  = threadIdx.x;
    const int lane = tid & 63;
    const int wid  = tid >> 6;
    const int wm   = wid >> 2;
    const int wn   = wid & 3;

    const int lr = tid >> 2;
    const int sc = ((tid & 3) ^ (lr & 3)) << 3;
    const bf16* aS  = Ag + (long)(mT * 128 + lr) * Dm + sc;
    const bf16* bS0 = Bg + (long)(nT * 256 + lr) * Dm + sc;
    const bf16* bS1 = bS0 + (long)128 * Dm;
    const int ldsW = wid << 9;

    const int fl = lane & 15;
    const int fh = lane >> 4;
    const int e0 = (fh ^ (fl & 3)) << 3;
    const int aro = (wm * 64 + fl) * 32;
    const int bro = (wn * 32 + fl) * 32;

    bf16x8 afr[4], b0r[2], b1r[2];
    f32x4 acc[4][2][2] = {};

#define STG(CI, PTR, T)                                                        \
    __builtin_amdgcn_global_load_lds((const AS1 void*)((PTR) + (T) * 32),      \
        (AS3 void*)&sm[CI][ldsW], 16, 0, 0);
#define STGG(G, T)                                                             \
    STG(3*(G) + 0, aS,  T) STG(3*(G) + 1, bS0, T) STG(3*(G) + 2, bS1, T)
#define RA(CI)                                                                 \
    _Pragma("unroll") for (int mm = 0; mm < 4; ++mm)                           \
        afr[mm] = *(const bf16x8*)&sm[CI][aro + mm * 512 + e0];
#define RB(BR, CI)                                                             \
    _Pragma("unroll") for (int nn = 0; nn < 2; ++nn)                           \
        BR[nn] = *(const bf16x8*)&sm[CI][bro + nn * 512 + e0];
#define RG(G)  RA(3*(G)) RB(b0r, 3*(G)+1) RB(b1r, 3*(G)+2)
#define MF16                                                                   \
    __builtin_amdgcn_s_setprio(1);                                             \
    _Pragma("unroll") for (int mm = 0; mm < 4; ++mm)                           \
    _Pragma("unroll") for (int nn = 0; nn < 2; ++nn)                           \
        acc[mm][0][nn] = __builtin_amdgcn_mfma_f32_16x16x32_bf16(              \
            afr[mm], b0r[nn], acc[mm][0][nn], 0, 0, 0);                        \
    _Pragma("unroll") for (int mm = 0; mm < 4; ++mm)                           \
    _Pragma("unroll") for (int nn = 0; nn < 2; ++nn)                           \
        acc[mm][1][nn] = __builtin_amdgcn_mfma_f32_16x16x32_bf16(              \
            afr[mm], b1r[nn], acc[mm][1][nn], 0, 0, 0);                        \
    __builtin_amdgcn_s_setprio(0);

    // prologue: g0 <- tile 0, g1 <- tile 1; confirm tile 0
    STGG(0, 0) STGG(1, 1)
    VM3; SB; BARR; SB;

    // main loop: 7 iters, phases read tiles t..t+2, stage tiles t+2..t+4
#pragma unroll 1
    for (int t = 0; t < NT - 3; t += 3) {
        // phase A: read g0 (tile t), stage g2 <- t+2; confirm t+1
        RG(0)
        STGG(2, t + 2)
        VM3; SB; BARR; LG0; SB;
        MF16
        SB; BARR; SB;
        // phase B: read g1 (tile t+1), stage g0 <- t+3; confirm t+2
        RG(1)
        STGG(0, t + 3)
        VM3; SB; BARR; LG0; SB;
        MF16
        SB; BARR; SB;
        // phase C: read g2 (tile t+2), stage g1 <- t+4; confirm t+3
        RG(2)
        STGG(1, t + 4)
        VM3; SB; BARR; LG0; SB;
        MF16
        SB; BARR; SB;
    }

    // tail: tiles 21,22,23
    {
        // phase 21: read g0 (tile 21), stage g2 <- 23; confirm 22
        RG(0)
        STGG(2, NT - 1)
        VM3; SB; BARR; LG0; SB;
        MF16
        SB; BARR; SB;
        // phase 22: read g1 (tile 22); confirm 23
        RG(1)
        VM0; SB; BARR; LG0; SB;
        MF16
        SB; BARR; SB;
        // phase 23: read g2 (tile 23)
        RG(2)
        SB; LG0; SB;
        MF16
    }

    // epilogue: nt dword stores; drain overlaps the co-resident block
    const int rB = mT * 128 + wm * 64 + fh * 4;
    const int cB = nT * 256 + wn * 32 + fl;
#pragma unroll
    for (int mm = 0; mm < 4; ++mm)
#pragma unroll
    for (int nq = 0; nq < 2; ++nq)
#pragma unroll
    for (int nn = 0; nn < 2; ++nn) {
        const int c = cB + nq * 128 + nn * 16;
        if (c >= Yv) continue;
        const int r = rB + mm * 16;
#pragma unroll
        for (int j = 0; j < 4; ++j)
            __builtin_nontemporal_store(acc[mm][nq][nn][j],
                                        Cg + (long)(r + j) * Yv + c);
    }
#undef STG
#undef STGG
#undef RA
#undef RB
#undef RG
#undef MF16
}

// ---------------------------------------------------------------------------
// Shared GEMM body: C[M][*] = A[M][K](lda) * B[*][K](ldb)^T, 128x128 tile.
// smem must be 128*32*2 bf16 (16 KiB). Verified m97 structure.
template<bool STORE_BF16>
DEV void gemm_core(bf16* __restrict__ smem,
                   const bf16* __restrict__ A, const bf16* __restrict__ Bm,
                   void* __restrict__ Cg, int bid, int M, int K,
                   int lda, int ldb, int ldc)
{
    bf16* As = smem;
    bf16* Bs = smem + 128 * 32;

    const int nTilesM = M >> 7;
    const int mTile = bid % nTilesM;
    const int nTile = bid / nTilesM;

    const int tid  = threadIdx.x;
    const int wave = tid >> 6;
    const int lane = tid & 63;

    const int sRow = (wave << 4) + (lane >> 2);
    const int sCol = (lane & 3) << 3;

    const long aBase = (long)(mTile * 128) * lda;
    const long bBase = (long)(nTile * 128) * ldb;

    const int fl = lane & 15;
    const int fh = lane >> 4;
    const int wRow = (wave >> 1) << 6;
    const int wCol = (wave & 1) << 6;

    f32x4 acc[4][4] = {};

    for (int k0 = 0; k0 < K; k0 += 32) {
#pragma unroll
        for (int t = 0; t < 2; ++t) {
            const bf16* gA = A  + aBase + (long)(t * 64 + sRow) * lda + (k0 + sCol);
            const bf16* gB = Bm + bBase + (long)(t * 64 + sRow) * ldb + (k0 + sCol);
            bf16* lA = &As[(t * 64 + (wave << 4)) * 32];
            bf16* lB = &Bs[(t * 64 + (wave << 4)) * 32];
            __builtin_amdgcn_global_load_lds(
                (const AS1 void*)gA, (AS3 void*)lA, 16, 0, 0);
            __builtin_amdgcn_global_load_lds(
                (const AS1 void*)gB, (AS3 void*)lB, 16, 0, 0);
        }
        __syncthreads();

        bf16x8 af[4], bfg[4];
#pragma unroll
        for (int m = 0; m < 4; ++m)
            af[m] = *(const bf16x8*)&As[(wRow + m * 16 + fl) * 32 + fh * 8];
#pragma unroll
        for (int n = 0; n < 4; ++n)
            bfg[n] = *(const bf16x8*)&Bs[(wCol + n * 16 + fl) * 32 + fh * 8];
#pragma unroll
        for (int m = 0; m < 4; ++m)
#pragma unroll
            for (int n = 0; n < 4; ++n)
                acc[m][n] = __builtin_amdgcn_mfma_f32_16x16x32_bf16(
                    af[m], bfg[n], acc[m][n], 0, 0, 0);
        __syncthreads();
    }

    const int rBase = mTile * 128 + wRow + fh * 4;
    const int cBase = nTile * 128 + wCol + fl;
#pragma unroll
    for (int m = 0; m < 4; ++m) {
#pragma unroll
        for (int n = 0; n < 4; ++n) {
            int gc = cBase + n * 16;
            int gr = rBase + m * 16;
            if (STORE_BF16) {
                bf16* C = (bf16*)Cg;
#pragma unroll
                for (int j = 0; j < 4; ++j)
                    C[(long)(gr + j) * ldc + gc] = __float2bfloat16(acc[m][n][j]);
            } else {
                float* C = (float*)Cg;
#pragma unroll
                for (int j = 0; j < 4; ++j)
                    C[(long)(gr + j) * ldc + gc] = acc[m][n][j];
            }
        }
    }
}

// batched wrapper (step 5)
template<bool STORE_BF16>
__global__ __launch_bounds__(256)
void gemm_bt(const bf16* __restrict__ Ag, const bf16* __restrict__ Bg,
             void* __restrict__ Cg, int M, int K,
             int lda, int ldb, int ldc, long sA, long sB, long sC)
{
    __shared__ bf16 smem[128 * 32 * 2];
    const int bz = blockIdx.z;
    char* C = (char*)Cg + (long)bz * sC * (STORE_BF16 ? 2 : 4);
    gemm_core<STORE_BF16>(smem, Ag + (long)bz * sA, Bg + (long)bz * sB,
                          (void*)C, blockIdx.x, M, K, lda, ldb, ldc);
}

// fused dual GEMM (step 2): blocks [0,192) QW = X@W_A^T ; [192,384) XWo^T = W_O^T@X^T
__global__ __launch_bounds__(256)
void gemm_dual(const bf16* __restrict__ Xb, const bf16* __restrict__ Wcat,
               bf16* __restrict__ QWb, bf16* __restrict__ XWoT)
{
    __shared__ bf16 smem[128 * 32 * 2];
    const int bid = blockIdx.x;
    if (bid < 192)
        gemm_core<true>(smem, Xb, Wcat, (void*)QWb, bid, Tok, Dm, Dm, Dm, Dm);
    else
        gemm_core<true>(smem, Wcat + (size_t)Dm * Dm, Xb, (void*)XWoT,
                        bid - 192, Dm, Dm, Dm, Dm, Tok);
}

// ---------------------------------------------------------------------------
// 64x128-tile GEMM (bf16 out): C[M][Nc] = A[M][K](lda) * B[Nc][K]^T
// 4 waves, each computes 64x32. For the logits GEMM (fills 256 blocks).
__global__ __launch_bounds__(256)
void gemm_bt64(const bf16* __restrict__ Ag, const bf16* __restrict__ Bg,
               bf16* __restrict__ Cg, int M, int K, int lda, int ldc,
               long sA, long sB, long sC)
{
    __shared__ bf16 As[64 * 32];
    __shared__ bf16 Bs[128 * 32];

    const int bz = blockIdx.z;
    const bf16* A  = Ag + (long)bz * sA;
    const bf16* Bm = Bg + (long)bz * sB;
    bf16* C = Cg + (long)bz * sC;

    const int bid = blockIdx.x;
    const int nTilesM = M >> 6;
    const int mTile = bid % nTilesM;
    const int nTile = bid / nTilesM;

    const int tid  = threadIdx.x;
    const int wave = tid >> 6;
    const int lane = tid & 63;

    const int sRow = tid >> 2;
    const int sCol = (tid & 3) << 3;

    const long aBase = (long)(mTile * 64) * lda;
    const long bBase = (long)(nTile * 128) * K;

    const int fl = lane & 15;
    const int fh = lane >> 4;

    f32x4 acc[4][2] = {};

    for (int k0 = 0; k0 < K; k0 += 32) {
        __builtin_amdgcn_global_load_lds(
            (const AS1 void*)(A + aBase + (long)sRow * lda + (k0 + sCol)),
            (AS3 void*)&As[wave * 512], 16, 0, 0);
#pragma unroll
        for (int t = 0; t < 2; ++t)
            __builtin_amdgcn_global_load_lds(
                (const AS1 void*)(Bm + bBase + (long)(t * 64 + sRow) * K + (k0 + sCol)),
                (AS3 void*)&Bs[t * 2048 + wave * 512], 16, 0, 0);
        __syncthreads();

        bf16x8 af[4], bfg[2];
#pragma unroll
        for (int m = 0; m < 4; ++m)
            af[m] = *(const bf16x8*)&As[(m * 16 + fl) * 32 + fh * 8];
#pragma unroll
        for (int n = 0; n < 2; ++n)
            bfg[n] = *(const bf16x8*)&Bs[(wave * 32 + n * 16 + fl) * 32 + fh * 8];
#pragma unroll
        for (int m = 0; m < 4; ++m)
#pragma unroll
            for (int n = 0; n < 2; ++n)
                acc[m][n] = __builtin_amdgcn_mfma_f32_16x16x32_bf16(
                    af[m], bfg[n], acc[m][n], 0, 0, 0);
        __syncthreads();
    }

    const int rBase = mTile * 64 + fh * 4;
    const int cBase = nTile * 128 + wave * 32 + fl;
#pragma unroll
    for (int m = 0; m < 4; ++m)
#pragma unroll
    for (int n = 0; n < 2; ++n) {
        const int gc = cBase + n * 16;
        const int gr = rBase + m * 16;
#pragma unroll
        for (int j = 0; j < 4; ++j)
            C[(long)(gr + j) * ldc + gc] = __float2bfloat16(acc[m][n][j]);
    }
}

// ---------------------------------------------------------------------------
// Fused prep: [0,11328) cvt_ey | [11328,12480) wT | [12480,16576) gather
static constexpr int PREP_CVT = 11328, PREP_WT = 1152, PREP_GATHER = 4096;

__global__ __launch_bounds__(256)
void k_prep(const float* __restrict__ Ey, bf16* __restrict__ Eyb,
            const float* __restrict__ WA, const float* __restrict__ WO,
            bf16* __restrict__ Wcat,
            const int* __restrict__ Ms, const float* __restrict__ Ev,
            bf16* __restrict__ Xb)
{
    __shared__ float t[32][33];
    const int b = blockIdx.x;
    const int tid = threadIdx.x;

    if (b < PREP_CVT) {
        const long idx = ((long)b * 256 + tid) * 8;
        const int row = (int)(idx / Dm);
        union { bf16 h[8]; uint4 u; } pk;
        if (row < Yv) {
            const f32x4* s = (const f32x4*)(Ey + idx);
            f32x4 a = __builtin_nontemporal_load(s);
            f32x4 c = __builtin_nontemporal_load(s + 1);
#pragma unroll
            for (int i = 0; i < 4; ++i) {
                pk.h[i]     = __float2bfloat16(a[i]);
                pk.h[4 + i] = __float2bfloat16(c[i]);
            }
        } else {
#pragma unroll
            for (int i = 0; i < 8; ++i) pk.h[i] = __float2bfloat16(0.f);
        }
        *(uint4*)(Eyb + idx) = pk.u;
    } else if (b < PREP_CVT + PREP_WT) {
        const int rem = b - PREP_CVT;
        const int z = rem / 576, r2 = rem % 576;
        const int bx = (r2 % 24) * 32, by = (r2 / 24) * 32;
        const float* W = z ? WO : WA;
        bf16* WT = Wcat + (size_t)z * Dm * Dm;
        const int tx = tid & 31, ty = tid >> 5;
#pragma unroll
        for (int i = 0; i < 32; i += 8)
            t[ty + i][tx] = W[(long)(bx + ty + i) * Dm + (by + tx)];
        __syncthreads();
#pragma unroll
        for (int i = 0; i < 32; i += 8)
            WT[(long)(by + ty + i) * Dm + (bx + tx)] = __float2bfloat16(t[tx][ty + i]);
    } else {
        const int token = b - (PREP_CVT + PREP_WT);
        if (tid < 192) {
            const int id = Ms[token];
            const int d = tid * 4;
            float4 v = *(const float4*)(Ev + (long)id * Dm + d);
            union { bf16 h[4]; uint2 u; } pk;
            pk.h[0] = __float2bfloat16(v.x); pk.h[1] = __float2bfloat16(v.y);
            pk.h[2] = __float2bfloat16(v.z); pk.h[3] = __float2bfloat16(v.w);
            *(uint2*)(Xb + (long)token * Dm + d) = pk.u;
        }
    }
}

// ---------------------------------------------------------------------------
DEV float waveMax(float v) {
#pragma unroll
    for (int o = 32; o > 0; o >>= 1) v = fmaxf(v, __shfl_xor(v, o, 64));
    return v;
}
DEV float waveSum(float v) {
#pragma unroll
    for (int o = 32; o > 0; o >>= 1) v += __shfl_xor(v, o, 64);
    return v;
}

// softmax over j of (L[b,i,j] + (j-i)) with mask; L is bf16, bias in f32
__global__ __launch_bounds__(256) void k_softmax(const bf16* __restrict__ L,
                                                 const int* __restrict__ Ms,
                                                 float* __restrict__ Aout,
                                                 bf16* __restrict__ Ab)
{
    __shared__ float red[8];
    int row = blockIdx.x;
    int b = row >> 9, i = row & 511;
    const bf16* l = L + (long)row * Nseq;
    const int* ms = Ms + (b << 9);
    int t = threadIdx.x;
    int wid = t >> 6, lane = t & 63;
    int j0 = t, j1 = t + 256;

    float a0 = __bfloat162float(l[j0]) + (float)(j0 - i);
    float a1 = __bfloat162float(l[j1]) + (float)(j1 - i);
    if (ms[j0] == 0) a0 = -1e12f;
    if (ms[j1] == 0) a1 = -1e12f;

    float m = waveMax(fmaxf(a0, a1));
    if (lane == 0) red[wid] = m;
    __syncthreads();
    m = fmaxf(fmaxf(red[0], red[1]), fmaxf(red[2], red[3]));

    float e0 = expf(a0 - m), e1 = expf(a1 - m);
    float s = waveSum(e0 + e1);
    if (lane == 0) red[4 + wid] = s;
    __syncthreads();
    s = red[4] + red[5] + red[6] + red[7];
    float inv = 1.0f / s;

    float r0 = e0 * inv, r1 = e1 * inv;
    __builtin_nontemporal_store(r0, &Aout[(long)row * Nseq + j0]);
    __builtin_nontemporal_store(r1, &Aout[(long)row * Nseq + j1]);
    Ab[(long)row * Nseq + j0] = __float2bfloat16(r0);
    Ab[(long)row * Nseq + j1] = __float2bfloat16(r1);
}

// H = LN(Qc + X) * gamma + beta  -> bf16  (Qc and X read as bf16)
__global__ __launch_bounds__(256) void k_ln(const bf16* __restrict__ Qc,
                                            const bf16* __restrict__ Xb,
                                            const float* __restrict__ gamma,
                                            const float* __restrict__ beta,
                                            bf16* __restrict__ Hb)
{
    __shared__ float red[8];
    int row = blockIdx.x;
    const bf16* q = Qc + (long)row * Dm;
    const bf16* e = Xb + (long)row * Dm;
    int t = threadIdx.x;
    int wid = t >> 6, lane = t & 63;

    float x[3];
#pragma unroll
    for (int c = 0; c < 3; ++c)
        x[c] = __bfloat162float(q[t + c * 256]) + __bfloat162float(e[t + c * 256]);

    float s = waveSum(x[0] + x[1] + x[2]);
    if (lane == 0) red[wid] = s;
    __syncthreads();
    float mu = (red[0] + red[1] + red[2] + red[3]) * (1.0f / 768.0f);

    float vs = 0.f;
#pragma unroll
    for (int c = 0; c < 3; ++c) { float d = x[c] - mu; vs += d * d; }
    vs = waveSum(vs);
    if (lane == 0) red[4 + wid] = vs;
    __syncthreads();
    float var = (red[4] + red[5] + red[6] + red[7]) * (1.0f / 768.0f);
    float rstd = rsqrtf(var + 1e-5f);

#pragma unroll
    for (int c = 0; c < 3; ++c) {
        int d = t + c * 256;
        Hb[(long)row * Dm + d] =
            __float2bfloat16((x[c] - mu) * rstd * gamma[d] + beta[d]);
    }
}

// ---------------------------------------------------------------------------
extern "C" void kernel_launch(void* const* d_in, const int* in_sizes, int n_in,
                              void* d_out, int out_size, void* d_ws, size_t ws_size,
                              hipStream_t stream)
{
    const int*   Ms    = (const int*)d_in[0];
    const float* Ev    = (const float*)d_in[1];
    const float* Ey    = (const float*)d_in[2];
    const float* WA    = (const float*)d_in[3];
    const float* WO    = (const float*)d_in[4];
    const float* gamma = (const float*)d_in[5];
    const float* beta  = (const float*)d_in[6];

    float* y_out = (float*)d_out;                       // [4096][30000]
    float* A_out = y_out + (size_t)Tok * Yv;            // [8][512][512]

    char* ws = (char*)d_ws;
    size_t off = 0;
    auto alloc = [&](size_t n) { char* p = ws + off; off += (n + 255) & ~(size_t)255; return p; };
    bf16*  Xb    = (bf16*) alloc((size_t)Tok * Dm * 2);
    bf16*  WcatT = (bf16*) alloc((size_t)2 * Dm * Dm * 2);
    bf16*  QWb   = (bf16*) alloc((size_t)Tok * Dm * 2);
    bf16*  XWoT  = (bf16*) alloc((size_t)Dm * Tok * 2);  // [768][4096]
    bf16*  Lb    = (bf16*) alloc((size_t)Tok * Nseq * 2);
    bf16*  Ab    = (bf16*) alloc((size_t)Tok * Nseq * 2);
    bf16*  Qcb   = (bf16*) alloc((size_t)Tok * Dm * 2);
    bf16*  Hb    = (bf16*) alloc((size_t)Tok * Dm * 2);
    bf16*  Eyb   = (bf16*) alloc((size_t)Ypad * Dm * 2);

    // 1. fused prep: E_y convert+pad | W transpose | embedding gather
    k_prep<<<dim3(PREP_CVT + PREP_WT + PREP_GATHER), dim3(256), 0, stream>>>(
        Ey, Eyb, WA, WO, WcatT, Ms, Ev, Xb);
    // 2. fused dual GEMM: QW = X@W_A^T  |  XWo^T = W_O^T@X^T  (384 blocks)
    gemm_dual<<<dim3(384), dim3(256), 0, stream>>>(Xb, WcatT, QWb, XWoT);
    // 3. logits = QW @ X^T per batch (bf16 out, 64x128 tiles, 256 blocks)
    gemm_bt64<<<dim3(32, 1, 8), dim3(256), 0, stream>>>(
        QWb, Xb, Lb, Nseq, Dm, Dm, Nseq,
        (long)Nseq * Dm, (long)Nseq * Dm, (long)Nseq * Nseq);
    // 4. bias + mask + softmax -> A (f32 in d_out, nt) and Ab (bf16)
    k_softmax<<<dim3(Tok), dim3(256), 0, stream>>>(Lb, Ms, A_out, Ab);
    // 5. Qc = A @ XWo per batch (bf16 out; B = XWo^T column-slice, ldb=4096)
    gemm_bt<true><<<dim3(24, 1, 8), dim3(256), 0, stream>>>(
        Ab, XWoT, (void*)Qcb, Nseq, Nseq, Nseq, Tok, Dm,
        (long)Nseq * Nseq, (long)Nseq, (long)Nseq * Dm);
    // 6. H = LN(Qc + X)
    k_ln<<<dim3(Tok), dim3(256), 0, stream>>>(Qcb, Xb, gamma, beta, Hb);
    // 7. y_logits = H @ E_y^T  (128x256 BK=32, 3-phase/3-K-tile, 2 blocks/CU)
    gemm_big<<<dim3(32 * (Ypad / 256)), dim3(512), 0, stream>>>(Hb, Eyb, y_out);
}

// Round 14
// 336.486 us; speedup vs baseline: 1.6315x; 1.0110x over previous
//
#include <hip/hip_runtime.h>
#include <hip/hip_bf16.h>

using bf16 = __hip_bfloat16;
typedef __attribute__((ext_vector_type(8))) short bf16x8;
typedef __attribute__((ext_vector_type(4))) float f32x4;

#define DEV __device__ __forceinline__

#define AS1 __attribute__((address_space(1)))
#define AS3 __attribute__((address_space(3)))
#define SB  __builtin_amdgcn_sched_barrier(0)
#define BARR __builtin_amdgcn_s_barrier()
#define LG0 asm volatile("s_waitcnt lgkmcnt(0)" ::: "memory")
#define VM3 asm volatile("s_waitcnt vmcnt(3)" ::: "memory")
#define VM0 asm volatile("s_waitcnt vmcnt(0)" ::: "memory")

// ---------------------------------------------------------------------------
// constants
static constexpr int Bsz = 8, Nseq = 512, Dm = 768, Vv = 30000, Yv = 30000;
static constexpr int Ypad = 30208;               // 118 tiles of 256
static constexpr int Tok = Bsz * Nseq;           // 4096
static constexpr int NT = Dm / 32;               // 24 K-tiles of 32

// ---------------------------------------------------------------------------
// Big GEMM (round-11 verified best): C[4096][Yv] f32 = A[4096][768]*B^T
// 128M x 256N tile, BK=32, 8 waves, 9 chunks (3 K-tile groups) = 72 KiB LDS
// -> 2 blocks/CU. 3 phases per 3 K-tiles (2 barriers/K-tile, 16 MFMA/phase),
// vmcnt(3) cadence, XOR-swizzle, XCD swizzle, nt stores.
// NOTE (r12 lesson): A-direct-to-VGPR variant spills (>128 VGPR at 2 blk/CU;
// WRITE_SIZE +176MB scratch) -- keep A staged through LDS.
__global__ __launch_bounds__(512, 4)
void gemm_big(const bf16* __restrict__ Ag, const bf16* __restrict__ Bg,
              float* __restrict__ Cg)
{
    __shared__ bf16 sm[9][4096];                 // 9 x 8 KiB = 72 KiB

    int bid = blockIdx.x;
    { int cpx = gridDim.x >> 3; bid = (bid & 7) * cpx + (bid >> 3); }
    const int mT = bid & 31;
    const int nT = bid >> 5;

    const int tid  = threadIdx.x;
    const int lane = tid & 63;
    const int wid  = tid >> 6;
    const int wm   = wid >> 2;
    const int wn   = wid & 3;

    const int lr = tid >> 2;
    const int sc = ((tid & 3) ^ (lr & 3)) << 3;
    const bf16* aS  = Ag + (long)(mT * 128 + lr) * Dm + sc;
    const bf16* bS0 = Bg + (long)(nT * 256 + lr) * Dm + sc;
    const bf16* bS1 = bS0 + (long)128 * Dm;
    const int ldsW = wid << 9;

    const int fl = lane & 15;
    const int fh = lane >> 4;
    const int e0 = (fh ^ (fl & 3)) << 3;
    const int aro = (wm * 64 + fl) * 32;
    const int bro = (wn * 32 + fl) * 32;

    bf16x8 afr[4], b0r[2], b1r[2];
    f32x4 acc[4][2][2] = {};

#define STG(CI, PTR, T)                                                        \
    __builtin_amdgcn_global_load_lds((const AS1 void*)((PTR) + (T) * 32),      \
        (AS3 void*)&sm[CI][ldsW], 16, 0, 0);
#define STGG(G, T)                                                             \
    STG(3*(G) + 0, aS,  T) STG(3*(G) + 1, bS0, T) STG(3*(G) + 2, bS1, T)
#define RA(CI)                                                                 \
    _Pragma("unroll") for (int mm = 0; mm < 4; ++mm)                           \
        afr[mm] = *(const bf16x8*)&sm[CI][aro + mm * 512 + e0];
#define RB(BR, CI)                                                             \
    _Pragma("unroll") for (int nn = 0; nn < 2; ++nn)                           \
        BR[nn] = *(const bf16x8*)&sm[CI][bro + nn * 512 + e0];
#define RG(G)  RA(3*(G)) RB(b0r, 3*(G)+1) RB(b1r, 3*(G)+2)
#define MF16                                                                   \
    __builtin_amdgcn_s_setprio(1);                                             \
    _Pragma("unroll") for (int mm = 0; mm < 4; ++mm)                           \
    _Pragma("unroll") for (int nn = 0; nn < 2; ++nn)                           \
        acc[mm][0][nn] = __builtin_amdgcn_mfma_f32_16x16x32_bf16(              \
            afr[mm], b0r[nn], acc[mm][0][nn], 0, 0, 0);                        \
    _Pragma("unroll") for (int mm = 0; mm < 4; ++mm)                           \
    _Pragma("unroll") for (int nn = 0; nn < 2; ++nn)                           \
        acc[mm][1][nn] = __builtin_amdgcn_mfma_f32_16x16x32_bf16(              \
            afr[mm], b1r[nn], acc[mm][1][nn], 0, 0, 0);                        \
    __builtin_amdgcn_s_setprio(0);

    // prologue: g0 <- tile 0, g1 <- tile 1; confirm tile 0
    STGG(0, 0) STGG(1, 1)
    VM3; SB; BARR; SB;

    // main loop: 7 iters, phases read tiles t..t+2, stage tiles t+2..t+4
#pragma unroll 1
    for (int t = 0; t < NT - 3; t += 3) {
        RG(0)
        STGG(2, t + 2)
        VM3; SB; BARR; LG0; SB;
        MF16
        SB; BARR; SB;
        RG(1)
        STGG(0, t + 3)
        VM3; SB; BARR; LG0; SB;
        MF16
        SB; BARR; SB;
        RG(2)
        STGG(1, t + 4)
        VM3; SB; BARR; LG0; SB;
        MF16
        SB; BARR; SB;
    }

    // tail: tiles 21,22,23
    {
        RG(0)
        STGG(2, NT - 1)
        VM3; SB; BARR; LG0; SB;
        MF16
        SB; BARR; SB;
        RG(1)
        VM0; SB; BARR; LG0; SB;
        MF16
        SB; BARR; SB;
        RG(2)
        SB; LG0; SB;
        MF16
    }

    // epilogue: nt dword stores; drain overlaps the co-resident block
    const int rB = mT * 128 + wm * 64 + fh * 4;
    const int cB = nT * 256 + wn * 32 + fl;
#pragma unroll
    for (int mm = 0; mm < 4; ++mm)
#pragma unroll
    for (int nq = 0; nq < 2; ++nq)
#pragma unroll
    for (int nn = 0; nn < 2; ++nn) {
        const int c = cB + nq * 128 + nn * 16;
        if (c >= Yv) continue;
        const int r = rB + mm * 16;
#pragma unroll
        for (int j = 0; j < 4; ++j)
            __builtin_nontemporal_store(acc[mm][nq][nn][j],
                                        Cg + (long)(r + j) * Yv + c);
    }
#undef STG
#undef STGG
#undef RA
#undef RB
#undef RG
#undef MF16
}

// ---------------------------------------------------------------------------
// Shared GEMM body: C[M][*] = A[M][K](lda) * B[*][K](ldb)^T, 128x128 tile.
// smem must be 128*32*2 bf16 (16 KiB). Verified m97 structure.
template<bool STORE_BF16>
DEV void gemm_core(bf16* __restrict__ smem,
                   const bf16* __restrict__ A, const bf16* __restrict__ Bm,
                   void* __restrict__ Cg, int bid, int M, int K,
                   int lda, int ldb, int ldc)
{
    bf16* As = smem;
    bf16* Bs = smem + 128 * 32;

    const int nTilesM = M >> 7;
    const int mTile = bid % nTilesM;
    const int nTile = bid / nTilesM;

    const int tid  = threadIdx.x;
    const int wave = tid >> 6;
    const int lane = tid & 63;

    const int sRow = (wave << 4) + (lane >> 2);
    const int sCol = (lane & 3) << 3;

    const long aBase = (long)(mTile * 128) * lda;
    const long bBase = (long)(nTile * 128) * ldb;

    const int fl = lane & 15;
    const int fh = lane >> 4;
    const int wRow = (wave >> 1) << 6;
    const int wCol = (wave & 1) << 6;

    f32x4 acc[4][4] = {};

    for (int k0 = 0; k0 < K; k0 += 32) {
#pragma unroll
        for (int t = 0; t < 2; ++t) {
            const bf16* gA = A  + aBase + (long)(t * 64 + sRow) * lda + (k0 + sCol);
            const bf16* gB = Bm + bBase + (long)(t * 64 + sRow) * ldb + (k0 + sCol);
            bf16* lA = &As[(t * 64 + (wave << 4)) * 32];
            bf16* lB = &Bs[(t * 64 + (wave << 4)) * 32];
            __builtin_amdgcn_global_load_lds(
                (const AS1 void*)gA, (AS3 void*)lA, 16, 0, 0);
            __builtin_amdgcn_global_load_lds(
                (const AS1 void*)gB, (AS3 void*)lB, 16, 0, 0);
        }
        __syncthreads();

        bf16x8 af[4], bfg[4];
#pragma unroll
        for (int m = 0; m < 4; ++m)
            af[m] = *(const bf16x8*)&As[(wRow + m * 16 + fl) * 32 + fh * 8];
#pragma unroll
        for (int n = 0; n < 4; ++n)
            bfg[n] = *(const bf16x8*)&Bs[(wCol + n * 16 + fl) * 32 + fh * 8];
#pragma unroll
        for (int m = 0; m < 4; ++m)
#pragma unroll
            for (int n = 0; n < 4; ++n)
                acc[m][n] = __builtin_amdgcn_mfma_f32_16x16x32_bf16(
                    af[m], bfg[n], acc[m][n], 0, 0, 0);
        __syncthreads();
    }

    const int rBase = mTile * 128 + wRow + fh * 4;
    const int cBase = nTile * 128 + wCol + fl;
#pragma unroll
    for (int m = 0; m < 4; ++m) {
#pragma unroll
        for (int n = 0; n < 4; ++n) {
            int gc = cBase + n * 16;
            int gr = rBase + m * 16;
            if (STORE_BF16) {
                bf16* C = (bf16*)Cg;
#pragma unroll
                for (int j = 0; j < 4; ++j)
                    C[(long)(gr + j) * ldc + gc] = __float2bfloat16(acc[m][n][j]);
            } else {
                float* C = (float*)Cg;
#pragma unroll
                for (int j = 0; j < 4; ++j)
                    C[(long)(gr + j) * ldc + gc] = acc[m][n][j];
            }
        }
    }
}

// batched wrapper (step 5)
template<bool STORE_BF16>
__global__ __launch_bounds__(256)
void gemm_bt(const bf16* __restrict__ Ag, const bf16* __restrict__ Bg,
             void* __restrict__ Cg, int M, int K,
             int lda, int ldb, int ldc, long sA, long sB, long sC)
{
    __shared__ bf16 smem[128 * 32 * 2];
    const int bz = blockIdx.z;
    char* C = (char*)Cg + (long)bz * sC * (STORE_BF16 ? 2 : 4);
    gemm_core<STORE_BF16>(smem, Ag + (long)bz * sA, Bg + (long)bz * sB,
                          (void*)C, blockIdx.x, M, K, lda, ldb, ldc);
}

// fused dual GEMM + E_y convert (step 2):
//   blocks [0,192):    QW = X @ W_A^T
//   blocks [192,384):  XWo^T = W_O^T @ X^T
//   blocks [384, 384+11328): E_y f32 -> bf16 [30208][768] (pad rows zero).
// cvt work is memory-bound and has NO dependency on X/Wcat -- it streams
// through spare occupancy while GEMM blocks own the MFMA pipes.
static constexpr int DUAL_CVT = 11328;

__global__ __launch_bounds__(256)
void gemm_dual(const bf16* __restrict__ Xb, const bf16* __restrict__ Wcat,
               bf16* __restrict__ QWb, bf16* __restrict__ XWoT,
               const float* __restrict__ Ey, bf16* __restrict__ Eyb)
{
    __shared__ bf16 smem[128 * 32 * 2];
    const int bid = blockIdx.x;
    if (bid < 192) {
        gemm_core<true>(smem, Xb, Wcat, (void*)QWb, bid, Tok, Dm, Dm, Dm, Dm);
    } else if (bid < 384) {
        gemm_core<true>(smem, Wcat + (size_t)Dm * Dm, Xb, (void*)XWoT,
                        bid - 192, Dm, Dm, Dm, Dm, Tok);
    } else {
        const int b = bid - 384;
        const long idx = ((long)b * 256 + threadIdx.x) * 8;
        const int row = (int)(idx / Dm);
        union { bf16 h[8]; uint4 u; } pk;
        if (row < Yv) {
            const f32x4* s = (const f32x4*)(Ey + idx);
            f32x4 a = __builtin_nontemporal_load(s);
            f32x4 c = __builtin_nontemporal_load(s + 1);
#pragma unroll
            for (int i = 0; i < 4; ++i) {
                pk.h[i]     = __float2bfloat16(a[i]);
                pk.h[4 + i] = __float2bfloat16(c[i]);
            }
        } else {
#pragma unroll
            for (int i = 0; i < 8; ++i) pk.h[i] = __float2bfloat16(0.f);
        }
        *(uint4*)(Eyb + idx) = pk.u;
    }
}

// ---------------------------------------------------------------------------
// 64x128-tile GEMM (bf16 out): C[M][Nc] = A[M][K](lda) * B[Nc][K]^T
// 4 waves, each computes 64x32. For the logits GEMM (fills 256 blocks).
__global__ __launch_bounds__(256)
void gemm_bt64(const bf16* __restrict__ Ag, const bf16* __restrict__ Bg,
               bf16* __restrict__ Cg, int M, int K, int lda, int ldc,
               long sA, long sB, long sC)
{
    __shared__ bf16 As[64 * 32];
    __shared__ bf16 Bs[128 * 32];

    const int bz = blockIdx.z;
    const bf16* A  = Ag + (long)bz * sA;
    const bf16* Bm = Bg + (long)bz * sB;
    bf16* C = Cg + (long)bz * sC;

    const int bid = blockIdx.x;
    const int nTilesM = M >> 6;
    const int mTile = bid % nTilesM;
    const int nTile = bid / nTilesM;

    const int tid  = threadIdx.x;
    const int wave = tid >> 6;
    const int lane = tid & 63;

    const int sRow = tid >> 2;
    const int sCol = (tid & 3) << 3;

    const long aBase = (long)(mTile * 64) * lda;
    const long bBase = (long)(nTile * 128) * K;

    const int fl = lane & 15;
    const int fh = lane >> 4;

    f32x4 acc[4][2] = {};

    for (int k0 = 0; k0 < K; k0 += 32) {
        __builtin_amdgcn_global_load_lds(
            (const AS1 void*)(A + aBase + (long)sRow * lda + (k0 + sCol)),
            (AS3 void*)&As[wave * 512], 16, 0, 0);
#pragma unroll
        for (int t = 0; t < 2; ++t)
            __builtin_amdgcn_global_load_lds(
                (const AS1 void*)(Bm + bBase + (long)(t * 64 + sRow) * K + (k0 + sCol)),
                (AS3 void*)&Bs[t * 2048 + wave * 512], 16, 0, 0);
        __syncthreads();

        bf16x8 af[4], bfg[2];
#pragma unroll
        for (int m = 0; m < 4; ++m)
            af[m] = *(const bf16x8*)&As[(m * 16 + fl) * 32 + fh * 8];
#pragma unroll
        for (int n = 0; n < 2; ++n)
            bfg[n] = *(const bf16x8*)&Bs[(wave * 32 + n * 16 + fl) * 32 + fh * 8];
#pragma unroll
        for (int m = 0; m < 4; ++m)
#pragma unroll
            for (int n = 0; n < 2; ++n)
                acc[m][n] = __builtin_amdgcn_mfma_f32_16x16x32_bf16(
                    af[m], bfg[n], acc[m][n], 0, 0, 0);
        __syncthreads();
    }

    const int rBase = mTile * 64 + fh * 4;
    const int cBase = nTile * 128 + wave * 32 + fl;
#pragma unroll
    for (int m = 0; m < 4; ++m)
#pragma unroll
    for (int n = 0; n < 2; ++n) {
        const int gc = cBase + n * 16;
        const int gr = rBase + m * 16;
#pragma unroll
        for (int j = 0; j < 4; ++j)
            C[(long)(gr + j) * ldc + gc] = __float2bfloat16(acc[m][n][j]);
    }
}

// ---------------------------------------------------------------------------
// Fused prep: [0,1152) wT | [1152,5248) gather   (cvt_ey moved to gemm_dual)
static constexpr int PREP_WT = 1152, PREP_GATHER = 4096;

__global__ __launch_bounds__(256)
void k_prep(const float* __restrict__ WA, const float* __restrict__ WO,
            bf16* __restrict__ Wcat,
            const int* __restrict__ Ms, const float* __restrict__ Ev,
            bf16* __restrict__ Xb)
{
    __shared__ float t[32][33];
    const int b = blockIdx.x;
    const int tid = threadIdx.x;

    if (b < PREP_WT) {
        const int z = b / 576, r2 = b % 576;
        const int bx = (r2 % 24) * 32, by = (r2 / 24) * 32;
        const float* W = z ? WO : WA;
        bf16* WT = Wcat + (size_t)z * Dm * Dm;
        const int tx = tid & 31, ty = tid >> 5;
#pragma unroll
        for (int i = 0; i < 32; i += 8)
            t[ty + i][tx] = W[(long)(bx + ty + i) * Dm + (by + tx)];
        __syncthreads();
#pragma unroll
        for (int i = 0; i < 32; i += 8)
            WT[(long)(by + ty + i) * Dm + (bx + tx)] = __float2bfloat16(t[tx][ty + i]);
    } else {
        const int token = b - PREP_WT;
        if (tid < 192) {
            const int id = Ms[token];
            const int d = tid * 4;
            float4 v = *(const float4*)(Ev + (long)id * Dm + d);
            union { bf16 h[4]; uint2 u; } pk;
            pk.h[0] = __float2bfloat16(v.x); pk.h[1] = __float2bfloat16(v.y);
            pk.h[2] = __float2bfloat16(v.z); pk.h[3] = __float2bfloat16(v.w);
            *(uint2*)(Xb + (long)token * Dm + d) = pk.u;
        }
    }
}

// ---------------------------------------------------------------------------
DEV float waveMax(float v) {
#pragma unroll
    for (int o = 32; o > 0; o >>= 1) v = fmaxf(v, __shfl_xor(v, o, 64));
    return v;
}
DEV float waveSum(float v) {
#pragma unroll
    for (int o = 32; o > 0; o >>= 1) v += __shfl_xor(v, o, 64);
    return v;
}

// softmax over j of (L[b,i,j] + (j-i)) with mask; L is bf16, bias in f32
__global__ __launch_bounds__(256) void k_softmax(const bf16* __restrict__ L,
                                                 const int* __restrict__ Ms,
                                                 float* __restrict__ Aout,
                                                 bf16* __restrict__ Ab)
{
    __shared__ float red[8];
    int row = blockIdx.x;
    int b = row >> 9, i = row & 511;
    const bf16* l = L + (long)row * Nseq;
    const int* ms = Ms + (b << 9);
    int t = threadIdx.x;
    int wid = t >> 6, lane = t & 63;
    int j0 = t, j1 = t + 256;

    float a0 = __bfloat162float(l[j0]) + (float)(j0 - i);
    float a1 = __bfloat162float(l[j1]) + (float)(j1 - i);
    if (ms[j0] == 0) a0 = -1e12f;
    if (ms[j1] == 0) a1 = -1e12f;

    float m = waveMax(fmaxf(a0, a1));
    if (lane == 0) red[wid] = m;
    __syncthreads();
    m = fmaxf(fmaxf(red[0], red[1]), fmaxf(red[2], red[3]));

    float e0 = expf(a0 - m), e1 = expf(a1 - m);
    float s = waveSum(e0 + e1);
    if (lane == 0) red[4 + wid] = s;
    __syncthreads();
    s = red[4] + red[5] + red[6] + red[7];
    float inv = 1.0f / s;

    float r0 = e0 * inv, r1 = e1 * inv;
    __builtin_nontemporal_store(r0, &Aout[(long)row * Nseq + j0]);
    __builtin_nontemporal_store(r1, &Aout[(long)row * Nseq + j1]);
    Ab[(long)row * Nseq + j0] = __float2bfloat16(r0);
    Ab[(long)row * Nseq + j1] = __float2bfloat16(r1);
}

// H = LN(Qc + X) * gamma + beta  -> bf16  (Qc and X read as bf16)
__global__ __launch_bounds__(256) void k_ln(const bf16* __restrict__ Qc,
                                            const bf16* __restrict__ Xb,
                                            const float* __restrict__ gamma,
                                            const float* __restrict__ beta,
                                            bf16* __restrict__ Hb)
{
    __shared__ float red[8];
    int row = blockIdx.x;
    const bf16* q = Qc + (long)row * Dm;
    const bf16* e = Xb + (long)row * Dm;
    int t = threadIdx.x;
    int wid = t >> 6, lane = t & 63;

    float x[3];
#pragma unroll
    for (int c = 0; c < 3; ++c)
        x[c] = __bfloat162float(q[t + c * 256]) + __bfloat162float(e[t + c * 256]);

    float s = waveSum(x[0] + x[1] + x[2]);
    if (lane == 0) red[wid] = s;
    __syncthreads();
    float mu = (red[0] + red[1] + red[2] + red[3]) * (1.0f / 768.0f);

    float vs = 0.f;
#pragma unroll
    for (int c = 0; c < 3; ++c) { float d = x[c] - mu; vs += d * d; }
    vs = waveSum(vs);
    if (lane == 0) red[4 + wid] = vs;
    __syncthreads();
    float var = (red[4] + red[5] + red[6] + red[7]) * (1.0f / 768.0f);
    float rstd = rsqrtf(var + 1e-5f);

#pragma unroll
    for (int c = 0; c < 3; ++c) {
        int d = t + c * 256;
        Hb[(long)row * Dm + d] =
            __float2bfloat16((x[c] - mu) * rstd * gamma[d] + beta[d]);
    }
}

// ---------------------------------------------------------------------------
extern "C" void kernel_launch(void* const* d_in, const int* in_sizes, int n_in,
                              void* d_out, int out_size, void* d_ws, size_t ws_size,
                              hipStream_t stream)
{
    const int*   Ms    = (const int*)d_in[0];
    const float* Ev    = (const float*)d_in[1];
    const float* Ey    = (const float*)d_in[2];
    const float* WA    = (const float*)d_in[3];
    const float* WO    = (const float*)d_in[4];
    const float* gamma = (const float*)d_in[5];
    const float* beta  = (const float*)d_in[6];

    float* y_out = (float*)d_out;                       // [4096][30000]
    float* A_out = y_out + (size_t)Tok * Yv;            // [8][512][512]

    char* ws = (char*)d_ws;
    size_t off = 0;
    auto alloc = [&](size_t n) { char* p = ws + off; off += (n + 255) & ~(size_t)255; return p; };
    bf16*  Xb    = (bf16*) alloc((size_t)Tok * Dm * 2);
    bf16*  WcatT = (bf16*) alloc((size_t)2 * Dm * Dm * 2);
    bf16*  QWb   = (bf16*) alloc((size_t)Tok * Dm * 2);
    bf16*  XWoT  = (bf16*) alloc((size_t)Dm * Tok * 2);  // [768][4096]
    bf16*  Lb    = (bf16*) alloc((size_t)Tok * Nseq * 2);
    bf16*  Ab    = (bf16*) alloc((size_t)Tok * Nseq * 2);
    bf16*  Qcb   = (bf16*) alloc((size_t)Tok * Dm * 2);
    bf16*  Hb    = (bf16*) alloc((size_t)Tok * Dm * 2);
    bf16*  Eyb   = (bf16*) alloc((size_t)Ypad * Dm * 2);

    // 1. prep: W transpose | embedding gather
    k_prep<<<dim3(PREP_WT + PREP_GATHER), dim3(256), 0, stream>>>(
        WA, WO, WcatT, Ms, Ev, Xb);
    // 2. fused: dual GEMM (QW | XWo^T) + E_y convert (overlapped, no dep)
    gemm_dual<<<dim3(384 + DUAL_CVT), dim3(256), 0, stream>>>(
        Xb, WcatT, QWb, XWoT, Ey, Eyb);
    // 3. logits = QW @ X^T per batch (bf16 out, 64x128 tiles, 256 blocks)
    gemm_bt64<<<dim3(32, 1, 8), dim3(256), 0, stream>>>(
        QWb, Xb, Lb, Nseq, Dm, Dm, Nseq,
        (long)Nseq * Dm, (long)Nseq * Dm, (long)Nseq * Nseq);
    // 4. bias + mask + softmax -> A (f32 in d_out, nt) and Ab (bf16)
    k_softmax<<<dim3(Tok), dim3(256), 0, stream>>>(Lb, Ms, A_out, Ab);
    // 5. Qc = A @ XWo per batch (bf16 out; B = XWo^T column-slice, ldb=4096)
    gemm_bt<true><<<dim3(24, 1, 8), dim3(256), 0, stream>>>(
        Ab, XWoT, (void*)Qcb, Nseq, Nseq, Nseq, Tok, Dm,
        (long)Nseq * Nseq, (long)Nseq, (long)Nseq * Dm);
    // 6. H = LN(Qc + X)
    k_ln<<<dim3(Tok), dim3(256), 0, stream>>>(Qcb, Xb, gamma, beta, Hb);
    // 7. y_logits = H @ E_y^T  (128x256 BK=32, 3-phase/3-K-tile, 2 blocks/CU)
    gemm_big<<<dim3(32 * (Ypad / 256)), dim3(512), 0, stream>>>(Hb, Eyb, y_out);
}